// Round 19
// baseline (221.576 us; speedup 1.0000x reference)
//
#include <hip/hip_runtime.h>
#include <stdint.h>

// QuantizedLinear (BitNet ternary): out = x @ q^T + bias
// INT8 path (absmax 3.06). R19: 256x256 i8 GEMM, A-only LDS (3x16KB),
// B in TRANSPOSED global layout Bt[k/64][n][64] -> per-wave B-fragment loads
// are contiguous 1KB segments (coalesced, L2-resident via XCD swizzle).
// One barrier + one counted VMW(6) + one LGKM0 per K-tile.

#define M_DIM 8192
#define N_DIM 4096
#define K_DIM 4096
#define BM 256
#define BN 256
#define BK 64

typedef __attribute__((ext_vector_type(4))) int vi4;

#define BAR() asm volatile("s_barrier" ::: "memory")
#define VMW(n) asm volatile("s_waitcnt vmcnt(" #n ")" ::: "memory")
#define SB0() __builtin_amdgcn_sched_barrier(0)
#define LGKM0()                                             \
  do {                                                      \
    SB0();                                                  \
    asm volatile("s_waitcnt lgkmcnt(0)" ::: "memory");      \
    SB0();                                                  \
  } while (0)

__device__ __forceinline__ void load_lds16(const void* g, void* l) {
  __builtin_amdgcn_global_load_lds(
      (const __attribute__((address_space(1))) void*)g,
      (__attribute__((address_space(3))) void*)l,
      16, 0, 0);
}

// ---------- K1: per-block partial sums of |w| (deterministic) ----------
__global__ __launch_bounds__(256) void k_abs_partial(const float* __restrict__ w,
                                                     double* __restrict__ partial) {
  const int tid = threadIdx.x;
  const size_t base = (size_t)blockIdx.x * 8192 + (size_t)tid * 4;
  double s = 0.0;
#pragma unroll
  for (int it = 0; it < 8; ++it) {
    const float4 v = *reinterpret_cast<const float4*>(w + base + (size_t)it * 1024);
    s += (double)fabsf(v.x) + (double)fabsf(v.y) + (double)fabsf(v.z) + (double)fabsf(v.w);
  }
  __shared__ double sd[256];
  sd[tid] = s;
  __syncthreads();
  for (int off = 128; off > 0; off >>= 1) {
    if (tid < off) sd[tid] += sd[tid + off];
    __syncthreads();
  }
  if (tid == 0) partial[blockIdx.x] = sd[0];
}

// ---------- K2: finalize gamma (fp32 like numpy) ----------
__global__ __launch_bounds__(256) void k_abs_final(const double* __restrict__ partial,
                                                   float* __restrict__ gamma_out) {
  const int tid = threadIdx.x;
  double s = 0.0;
  for (int i = tid; i < 2048; i += 256) s += partial[i];
  __shared__ double sd[256];
  sd[tid] = s;
  __syncthreads();
  for (int off = 128; off > 0; off >>= 1) {
    if (tid < off) sd[tid] += sd[tid + off];
    __syncthreads();
  }
  if (tid == 0) {
    float g = (float)(sd[0] / 16777216.0);  // mean over 4096*4096
    gamma_out[0] = g + 1e-5f;
  }
}

// ---------- K3: quantize W -> ternary int8, TRANSPOSED Bt[k/64][n][64] ------
// thread f handles w[o][i0..i0+3]; writes 4B to Bt + (i0>>6)*(N*64) + o*64 + (i0&63).
// 16 consecutive threads cover one o's 64 i's -> 64B contiguous runs; coalesced.
__global__ __launch_bounds__(256) void k_quant(const float* __restrict__ w,
                                               const float* __restrict__ gamma_p,
                                               signed char* __restrict__ bt) {
  const float g = gamma_p[0];
  const size_t n4 = (size_t)N_DIM * K_DIM / 4;
  const size_t stride = (size_t)gridDim.x * blockDim.x;
  for (size_t f = (size_t)blockIdx.x * blockDim.x + threadIdx.x; f < n4; f += stride) {
    const float4 v = reinterpret_cast<const float4*>(w)[f];
    float r;
    int a, b, c, d;
    r = rintf(v.x / g); a = (r >= 1.0f) ? 1 : ((r <= -1.0f) ? -1 : 0);
    r = rintf(v.y / g); b = (r >= 1.0f) ? 1 : ((r <= -1.0f) ? -1 : 0);
    r = rintf(v.z / g); c = (r >= 1.0f) ? 1 : ((r <= -1.0f) ? -1 : 0);
    r = rintf(v.w / g); d = (r >= 1.0f) ? 1 : ((r <= -1.0f) ? -1 : 0);
    const int o = (int)(f >> 10);          // out-feature (B's n)
    const int i0 = ((int)f & 1023) << 2;   // in-feature (k)
    const size_t dst = (size_t)(i0 >> 6) * (N_DIM * 64) + (size_t)o * 64 + (i0 & 63);
    *reinterpret_cast<int*>(bt + dst) =
        (a & 0xff) | ((b & 0xff) << 8) | ((c & 0xff) << 16) | ((d & 0xff) << 24);
  }
}

// ---------- K4: x fp32 -> per-row-scaled int8 ----------
__global__ __launch_bounds__(256) void k_quant_x(const float* __restrict__ x,
                                                 signed char* __restrict__ xq,
                                                 float* __restrict__ xs) {
  const int row = blockIdx.x;  // 8192
  const int tid = threadIdx.x;
  const float* xr = x + (size_t)row * K_DIM;
  float4 v[4];
  float am = 0.0f;
#pragma unroll
  for (int i = 0; i < 4; ++i) {
    v[i] = reinterpret_cast<const float4*>(xr)[tid * 4 + i];
    am = fmaxf(am, fmaxf(fmaxf(fabsf(v[i].x), fabsf(v[i].y)),
                         fmaxf(fabsf(v[i].z), fabsf(v[i].w))));
  }
  for (int off = 32; off > 0; off >>= 1) am = fmaxf(am, __shfl_down(am, off));
  __shared__ float sm[4];
  if ((tid & 63) == 0) sm[tid >> 6] = am;
  __syncthreads();
  const float bm = fmaxf(fmaxf(fmaxf(sm[0], sm[1]), fmaxf(sm[2], sm[3])), 1e-20f);
  if (tid == 0) xs[row] = bm / 127.0f;
  const float inv = 127.0f / bm;
  union { signed char c[16]; int4 q; } u;
#pragma unroll
  for (int i = 0; i < 4; ++i) {
    u.c[i * 4 + 0] = (signed char)(int)rintf(v[i].x * inv);
    u.c[i * 4 + 1] = (signed char)(int)rintf(v[i].y * inv);
    u.c[i * 4 + 2] = (signed char)(int)rintf(v[i].z * inv);
    u.c[i * 4 + 3] = (signed char)(int)rintf(v[i].w * inv);
  }
  *reinterpret_cast<int4*>(xq + (size_t)row * K_DIM + tid * 16) = u.q;
}

// ---------- K5: 256x256 i8 GEMM, A-only LDS, B via transposed global ----------
// A LDS swizzle (verified R13/R15): 64B rows = 4x16B slots; logical slot c at
// phys slot c ^ ((row>>1)&3); inverse-swizzled glds source + swizzled ds_read.
__global__ __launch_bounds__(512, 2) void k_gemm(const signed char* __restrict__ Aq,
                                                 const signed char* __restrict__ Bt,
                                                 const float* __restrict__ xs,
                                                 const float* __restrict__ bias,
                                                 float* __restrict__ C) {
  __shared__ unsigned char lds[3][256][64];  // 48 KiB, A tiles only

  const int tid = threadIdx.x;
  const int wid = tid >> 6;   // 0..7
  const int lane = tid & 63;
  const int wm = wid >> 2;    // 0..1
  const int wn = wid & 3;     // 0..3
  const int l15 = lane & 15;
  const int l4 = lane >> 4;   // 0..3

  // bijective XCD col-chunk swizzle: 512 blocks = 8 XCDs x 64; XCD c owns
  // bx in {2c, 2c+1} (its 2 B col-panels = 2MB i8, L2-resident), all by.
  const int c8 = blockIdx.x & 7;
  const int idx = blockIdx.x >> 3;
  const int bcol = (c8 * 2 + (idx & 1)) * BN;
  const int brow = (idx >> 1) * BM;

  // A staging: lane covers (row = wid*16 + lane>>2, slot = lane&3) of a 128-row half
  const int srow = wid * 16 + (lane >> 2);
  const int scol = ((lane & 3) ^ ((lane >> 3) & 3)) << 4;
  // ds_read: phys slot = l4 ^ ((row>>1)&3); row ≡ l15 (mod 16)
  const int rdoff = ((l4 ^ ((l15 >> 1) & 3)) << 4);

  // B: Bt[kt][n][64]; lane reads n = bcol + p*64 + wn*16 + l15, bytes l4*16..+15
  // -> for fixed p, the wave's 16x64B = 1KB contiguous. 4 loads/tile.
  const signed char* bb =
      Bt + (size_t)(bcol + wn * 16 + l15) * 64 + l4 * 16;

#define STAGE_A(buf, kt)                                                           \
  do {                                                                             \
    load_lds16(Aq + (size_t)(brow + srow) * K_DIM + (kt)*64 + scol,                \
               (char*)&lds[buf][0][0] + (size_t)wid * 1024);                       \
    load_lds16(Aq + (size_t)(brow + 128 + srow) * K_DIM + (kt)*64 + scol,          \
               (char*)&lds[buf][128][0] + (size_t)wid * 1024);                     \
    SB0();                                                                         \
  } while (0)

#define GLB_B(BR, kt)                                                              \
  do {                                                                             \
    _Pragma("unroll") for (int p = 0; p < 4; ++p)                                  \
      BR[p] = *reinterpret_cast<const vi4*>(                                       \
          bb + (size_t)(kt) * (N_DIM * 64) + (size_t)(p * 64) * 64);               \
    SB0();                                                                         \
  } while (0)

#define RD_A8(F, buf)                                                              \
  do {                                                                             \
    _Pragma("unroll") for (int i = 0; i < 8; ++i)                                  \
      F[i] = *reinterpret_cast<const vi4*>(                                        \
          &lds[buf][0][0] + (size_t)(wm * 128 + i * 16 + l15) * 64 + rdoff);       \
    SB0();                                                                         \
  } while (0)

#define MFMA32(F, BR)                                                              \
  do {                                                                             \
    __builtin_amdgcn_s_setprio(1);                                                 \
    _Pragma("unroll") for (int i = 0; i < 8; ++i)                                  \
      _Pragma("unroll") for (int p = 0; p < 4; ++p)                                \
        acc[i][p] = __builtin_amdgcn_mfma_i32_16x16x64_i8(F[i], BR[p],             \
                                                          acc[i][p], 0, 0, 0);     \
    __builtin_amdgcn_s_setprio(0);                                                 \
  } while (0)

  vi4 acc[8][4];
#pragma unroll
  for (int i = 0; i < 8; ++i)
#pragma unroll
    for (int p = 0; p < 4; ++p)
#pragma unroll
      for (int e = 0; e < 4; ++e) acc[i][p][e] = 0;

  vi4 fr[8], bA[4], bB[4];

  // prologue: A(0)->buf0, A(1)->buf1, B(0)->bA; full drain once, one barrier
  STAGE_A(0, 0);
  STAGE_A(1, 1);
  GLB_B(bA, 0);
  VMW(0);
  BAR();

  int cur = 0;
  // steady: tiles (t, t+1), t = 0..60 step 2 -> covers tiles 0..61
  for (int t = 0; t < 62; t += 2) {
    const int b1 = (cur == 2) ? 0 : cur + 1;
    const int b2 = (b1 == 2) ? 0 : b1 + 1;
    // ---- tile t (B in bA) ----
    RD_A8(fr, cur);
    GLB_B(bB, t + 1);
    STAGE_A(b2, t + 2);
    VMW(6);   // B(t)+A(t+1) landed (outstanding: B(t+1)4 + A(t+2)2)
    LGKM0();
    MFMA32(fr, bA);
    BAR();    // publish buf b1 = A(t+1); buf cur free after this wave's reads
    // ---- tile t+1 (B in bB) ----
    RD_A8(fr, b1);
    GLB_B(bA, t + 2);
    STAGE_A(cur, t + 3);  // t+3 <= 63
    VMW(6);
    LGKM0();
    MFMA32(fr, bB);
    BAR();
    cur = b2;
  }
  // ---- tile 62 (cur == 2, B in bA) ----
  RD_A8(fr, cur);
  GLB_B(bB, 63);
  VMW(4);   // B(62)+A(63) landed (outstanding: B(63)4)
  LGKM0();
  MFMA32(fr, bA);
  BAR();
  // ---- tile 63 (buf 0, B in bB) ----
  RD_A8(fr, 0);
  VMW(0);
  LGKM0();
  MFMA32(fr, bB);

  // ---- epilogue: C/D layout col=lane&15, row=(lane>>4)*4+j; dequant + bias ----
  float bi[4];
#pragma unroll
  for (int p = 0; p < 4; ++p) bi[p] = bias[bcol + p * 64 + wn * 16 + l15];
#pragma unroll
  for (int i = 0; i < 8; ++i) {
#pragma unroll
    for (int j = 0; j < 4; ++j) {
      const int row = brow + wm * 128 + i * 16 + l4 * 4 + j;
      const float sc = xs[row];
      float* crow = C + (size_t)row * N_DIM + bcol + wn * 16 + l15;
#pragma unroll
      for (int p = 0; p < 4; ++p) crow[p * 64] = (float)acc[i][p][j] * sc + bi[p];
    }
  }
#undef STAGE_A
#undef GLB_B
#undef RD_A8
#undef MFMA32
}

extern "C" void kernel_launch(void* const* d_in, const int* in_sizes, int n_in,
                              void* d_out, int out_size, void* d_ws, size_t ws_size,
                              hipStream_t stream) {
  (void)in_sizes; (void)n_in; (void)out_size; (void)ws_size;
  const float* x = (const float*)d_in[0];
  const float* w = (const float*)d_in[1];
  const float* bias = (const float*)d_in[2];
  float* out = (float*)d_out;

  char* ws = (char*)d_ws;
  signed char* xq = (signed char*)ws;                                   // 32 MB
  signed char* bt = (signed char*)(ws + (size_t)M_DIM * K_DIM);         // 16 MB (transposed)
  float* xs = (float*)(ws + (size_t)M_DIM * K_DIM + (size_t)N_DIM * K_DIM);  // 32 KB
  double* partial = (double*)((char*)xs + M_DIM * sizeof(float));
  float* gamma = (float*)(partial + 2048);

  k_abs_partial<<<2048, 256, 0, stream>>>(w, partial);
  k_abs_final<<<1, 256, 0, stream>>>(partial, gamma);
  k_quant<<<2048, 256, 0, stream>>>(w, gamma, bt);
  k_quant_x<<<M_DIM, 256, 0, stream>>>(x, xq, xs);

  k_gemm<<<512, 512, 0, stream>>>(xq, bt, xs, bias, out);
}

// Round 23
// 208.378 us; speedup vs baseline: 1.0633x; 1.0633x over previous
//
#include <hip/hip_runtime.h>
#include <stdint.h>

// QuantizedLinear (BitNet ternary): out = x @ q^T + bias
// INT8 path (absmax 3.06). R20 = R18 geometry (128x256 block, 64x64 wave
// tiles) with co-residency made to FIT: launch_bounds(512,4) caps regs at
// 128/wave (acc 64 AGPR + ~55 VGPR), LDS 2 buffers = 48KB -> 2 blocks/CU.
// Cross-block dephasing provides the LDS<->MFMA overlap no 1-block schedule
// achieved (R10/R12/R15/R19). Verified i8 swizzle + XCD chunk swizzle.

#define M_DIM 8192
#define N_DIM 4096
#define K_DIM 4096
#define BM 128
#define BN 256
#define BK 64

typedef __attribute__((ext_vector_type(4))) int vi4;

#define BAR() asm volatile("s_barrier" ::: "memory")
#define VMW0() asm volatile("s_waitcnt vmcnt(0)" ::: "memory")
#define SB0() __builtin_amdgcn_sched_barrier(0)
#define LGKM0()                                             \
  do {                                                      \
    SB0();                                                  \
    asm volatile("s_waitcnt lgkmcnt(0)" ::: "memory");      \
    SB0();                                                  \
  } while (0)

__device__ __forceinline__ void load_lds16(const void* g, void* l) {
  __builtin_amdgcn_global_load_lds(
      (const __attribute__((address_space(1))) void*)g,
      (__attribute__((address_space(3))) void*)l,
      16, 0, 0);
}

// ---------- K1: per-block partial sums of |w| (deterministic) ----------
__global__ __launch_bounds__(256) void k_abs_partial(const float* __restrict__ w,
                                                     double* __restrict__ partial) {
  const int tid = threadIdx.x;
  const size_t base = (size_t)blockIdx.x * 8192 + (size_t)tid * 4;
  double s = 0.0;
#pragma unroll
  for (int it = 0; it < 8; ++it) {
    const float4 v = *reinterpret_cast<const float4*>(w + base + (size_t)it * 1024);
    s += (double)fabsf(v.x) + (double)fabsf(v.y) + (double)fabsf(v.z) + (double)fabsf(v.w);
  }
  __shared__ double sd[256];
  sd[tid] = s;
  __syncthreads();
  for (int off = 128; off > 0; off >>= 1) {
    if (tid < off) sd[tid] += sd[tid + off];
    __syncthreads();
  }
  if (tid == 0) partial[blockIdx.x] = sd[0];
}

// ---------- K2: finalize gamma (fp32 like numpy) ----------
__global__ __launch_bounds__(256) void k_abs_final(const double* __restrict__ partial,
                                                   float* __restrict__ gamma_out) {
  const int tid = threadIdx.x;
  double s = 0.0;
  for (int i = tid; i < 2048; i += 256) s += partial[i];
  __shared__ double sd[256];
  sd[tid] = s;
  __syncthreads();
  for (int off = 128; off > 0; off >>= 1) {
    if (tid < off) sd[tid] += sd[tid + off];
    __syncthreads();
  }
  if (tid == 0) {
    float g = (float)(sd[0] / 16777216.0);  // mean over 4096*4096
    gamma_out[0] = g + 1e-5f;
  }
}

// ---------- K3: quantize W -> ternary int8 ----------
__global__ __launch_bounds__(256) void k_quant(const float* __restrict__ w,
                                               const float* __restrict__ gamma_p,
                                               int* __restrict__ qb) {
  const float g = gamma_p[0];
  const size_t n4 = (size_t)N_DIM * K_DIM / 4;
  const size_t stride = (size_t)gridDim.x * blockDim.x;
  for (size_t i = (size_t)blockIdx.x * blockDim.x + threadIdx.x; i < n4; i += stride) {
    const float4 v = reinterpret_cast<const float4*>(w)[i];
    float r;
    int a, b, c, d;
    r = rintf(v.x / g); a = (r >= 1.0f) ? 1 : ((r <= -1.0f) ? -1 : 0);
    r = rintf(v.y / g); b = (r >= 1.0f) ? 1 : ((r <= -1.0f) ? -1 : 0);
    r = rintf(v.z / g); c = (r >= 1.0f) ? 1 : ((r <= -1.0f) ? -1 : 0);
    r = rintf(v.w / g); d = (r >= 1.0f) ? 1 : ((r <= -1.0f) ? -1 : 0);
    qb[i] = (a & 0xff) | ((b & 0xff) << 8) | ((c & 0xff) << 16) | ((d & 0xff) << 24);
  }
}

// ---------- K4: x fp32 -> per-row-scaled int8 ----------
__global__ __launch_bounds__(256) void k_quant_x(const float* __restrict__ x,
                                                 signed char* __restrict__ xq,
                                                 float* __restrict__ xs) {
  const int row = blockIdx.x;  // 8192
  const int tid = threadIdx.x;
  const float* xr = x + (size_t)row * K_DIM;
  float4 v[4];
  float am = 0.0f;
#pragma unroll
  for (int i = 0; i < 4; ++i) {
    v[i] = reinterpret_cast<const float4*>(xr)[tid * 4 + i];
    am = fmaxf(am, fmaxf(fmaxf(fabsf(v[i].x), fabsf(v[i].y)),
                         fmaxf(fabsf(v[i].z), fabsf(v[i].w))));
  }
  for (int off = 32; off > 0; off >>= 1) am = fmaxf(am, __shfl_down(am, off));
  __shared__ float sm[4];
  if ((tid & 63) == 0) sm[tid >> 6] = am;
  __syncthreads();
  const float bm = fmaxf(fmaxf(fmaxf(sm[0], sm[1]), fmaxf(sm[2], sm[3])), 1e-20f);
  if (tid == 0) xs[row] = bm / 127.0f;
  const float inv = 127.0f / bm;
  union { signed char c[16]; int4 q; } u;
#pragma unroll
  for (int i = 0; i < 4; ++i) {
    u.c[i * 4 + 0] = (signed char)(int)rintf(v[i].x * inv);
    u.c[i * 4 + 1] = (signed char)(int)rintf(v[i].y * inv);
    u.c[i * 4 + 2] = (signed char)(int)rintf(v[i].z * inv);
    u.c[i * 4 + 3] = (signed char)(int)rintf(v[i].w * inv);
  }
  *reinterpret_cast<int4*>(xq + (size_t)row * K_DIM + tid * 16) = u.q;
}

// ---------- K5: 128x256 i8 MFMA GEMM, 64x64 wave tiles, 2 blocks/CU ----------
// i8 LDS swizzle (verified R13/R15/R18): 64B rows = 4x16B slots; logical slot
// c at phys slot c ^ ((row>>1)&3); inverse-swizzled glds source + swizzled
// ds_read. Per buffer: A[128][64] at 0 (8KB), B[256][64] at 8192 (16KB).
__global__ __launch_bounds__(512, 4) void k_gemm(const signed char* __restrict__ Aq,
                                                 const signed char* __restrict__ Bq,
                                                 const float* __restrict__ xs,
                                                 const float* __restrict__ bias,
                                                 float* __restrict__ C) {
  __shared__ unsigned char lds[2][24576];  // 48 KiB -> 2 blocks/CU (96 KiB)

  const int tid = threadIdx.x;
  const int wid = tid >> 6;   // 0..7
  const int lane = tid & 63;
  const int wm = wid >> 2;    // 0..1 (row half)
  const int wn = wid & 3;     // 0..3 (col quarter)
  const int l15 = lane & 15;
  const int l4 = lane >> 4;   // 0..3

  // bijective XCD col-chunk swizzle: 1024 blocks = 8 XCDs x 128; XCD c owns
  // B col-panels {2c, 2c+1} (2MB i8, L2-resident); rows stream.
  const int c8 = blockIdx.x & 7;
  const int idx = blockIdx.x >> 3;            // 0..127
  const int bcol = (c8 * 2 + (idx & 1)) * BN;
  const int brow = (idx >> 1) * BM;

  // staging: thread covers (row = tid>>2, slot = tid&3); source pre-inverse-swizzled
  const int srow = tid >> 2;
  const int scol = ((tid & 3) ^ ((tid >> 3) & 3)) << 4;
  // ds_read: phys slot = l4 ^ ((row>>1)&3)
  const int rdoff = ((l4 ^ ((l15 >> 1) & 3)) << 4);

#define STAGE_ALL(buf, kt)                                                          \
  do {                                                                              \
    load_lds16(Aq + (size_t)(brow + srow) * K_DIM + (kt)*64 + scol,                 \
               (char*)&lds[buf][0] + (size_t)wid * 1024);                           \
    load_lds16(Bq + (size_t)(bcol + srow) * K_DIM + (kt)*64 + scol,                 \
               (char*)&lds[buf][8192] + (size_t)wid * 1024);                        \
    load_lds16(Bq + (size_t)(bcol + 128 + srow) * K_DIM + (kt)*64 + scol,           \
               (char*)&lds[buf][16384] + (size_t)wid * 1024);                       \
    SB0();                                                                          \
  } while (0)

#define RD8(buf)                                                                    \
  do {                                                                              \
    _Pragma("unroll") for (int i = 0; i < 4; ++i)                                   \
      fa[i] = *reinterpret_cast<const vi4*>(                                        \
          &lds[buf][0] + (size_t)(wm * 64 + i * 16 + l15) * 64 + rdoff);            \
    _Pragma("unroll") for (int p = 0; p < 4; ++p)                                   \
      fb[p] = *reinterpret_cast<const vi4*>(                                        \
          &lds[buf][8192] + (size_t)(wn * 64 + p * 16 + l15) * 64 + rdoff);         \
    SB0();                                                                          \
  } while (0)

#define MFMA16()                                                                    \
  do {                                                                              \
    __builtin_amdgcn_s_setprio(1);                                                  \
    _Pragma("unroll") for (int i = 0; i < 4; ++i)                                   \
      _Pragma("unroll") for (int p = 0; p < 4; ++p)                                 \
        acc[i][p] = __builtin_amdgcn_mfma_i32_16x16x64_i8(fa[i], fb[p],             \
                                                          acc[i][p], 0, 0, 0);      \
    __builtin_amdgcn_s_setprio(0);                                                  \
  } while (0)

  vi4 acc[4][4];
#pragma unroll
  for (int i = 0; i < 4; ++i)
#pragma unroll
    for (int p = 0; p < 4; ++p)
#pragma unroll
      for (int e = 0; e < 4; ++e) acc[i][p][e] = 0;

  vi4 fa[4], fb[4];

  // prologue: tile0 -> buf0
  STAGE_ALL(0, 0);
  VMW0();
  BAR();

  // double-buffer: compute tile t from buf t&1; stage t+1 into other buf.
  for (int t = 0; t < 63; ++t) {
    const int cur = t & 1;
    RD8(cur);                   // 8 ds_read_b128 (tile t)
    STAGE_ALL(cur ^ 1, t + 1);  // 3 glds (tile t+1); different buffer, WAR-safe
    LGKM0();                    // own frags landed
    MFMA16();                   // ~670 cyc covers most of stage latency
    VMW0();                     // tile t+1 staged
    BAR();                      // publish; prior reads all drained (pre-LGKM0)
  }
  // tile 63 (buf 1)
  RD8(1);
  LGKM0();
  MFMA16();

  // ---- epilogue: C/D layout col=lane&15, row=(lane>>4)*4+j; dequant + bias ----
  float bi[4];
#pragma unroll
  for (int p = 0; p < 4; ++p) bi[p] = bias[bcol + wn * 64 + p * 16 + l15];
#pragma unroll
  for (int i = 0; i < 4; ++i) {
#pragma unroll
    for (int j = 0; j < 4; ++j) {
      const int row = brow + wm * 64 + i * 16 + l4 * 4 + j;
      const float sc = xs[row];
      float* crow = C + (size_t)row * N_DIM + bcol + wn * 64 + l15;
#pragma unroll
      for (int p = 0; p < 4; ++p) crow[p * 16] = (float)acc[i][p][j] * sc + bi[p];
    }
  }
#undef STAGE_ALL
#undef RD8
#undef MFMA16
}

extern "C" void kernel_launch(void* const* d_in, const int* in_sizes, int n_in,
                              void* d_out, int out_size, void* d_ws, size_t ws_size,
                              hipStream_t stream) {
  (void)in_sizes; (void)n_in; (void)out_size; (void)ws_size;
  const float* x = (const float*)d_in[0];
  const float* w = (const float*)d_in[1];
  const float* bias = (const float*)d_in[2];
  float* out = (float*)d_out;

  char* ws = (char*)d_ws;
  signed char* xq = (signed char*)ws;                                   // 32 MB
  signed char* qb = (signed char*)(ws + (size_t)M_DIM * K_DIM);         // 16 MB
  float* xs = (float*)(ws + (size_t)M_DIM * K_DIM + (size_t)N_DIM * K_DIM);  // 32 KB
  double* partial = (double*)((char*)xs + M_DIM * sizeof(float));
  float* gamma = (float*)(partial + 2048);

  k_abs_partial<<<2048, 256, 0, stream>>>(w, partial);
  k_abs_final<<<1, 256, 0, stream>>>(partial, gamma);
  k_quant<<<2048, 256, 0, stream>>>(w, gamma, (int*)qb);
  k_quant_x<<<M_DIM, 256, 0, stream>>>(x, xq, xs);

  k_gemm<<<1024, 512, 0, stream>>>(xq, qb, xs, bias, out);
}

// Round 24
// 203.107 us; speedup vs baseline: 1.0909x; 1.0260x over previous
//
#include <hip/hip_runtime.h>
#include <stdint.h>

// QuantizedLinear (BitNet ternary): out = x @ q^T + bias
// INT8 path (absmax 3.06). R24 = R18's 3-buffer counted-vmcnt schedule
// (stage t+2, VMW(3) publish, no vmcnt(0) mid-loop — HW-verified correct)
// + R23's launch_bounds(512,4) reg cap (HW-verified 2 blocks/CU, occ 41%).
// 128x256 block, 64x64 wave tiles, LDS 3x24KB=72KB (144KB/CU for 2 blocks).

#define M_DIM 8192
#define N_DIM 4096
#define K_DIM 4096
#define BM 128
#define BN 256
#define BK 64

typedef __attribute__((ext_vector_type(4))) int vi4;

#define BAR() asm volatile("s_barrier" ::: "memory")
#define VMW3() asm volatile("s_waitcnt vmcnt(3)" ::: "memory")
#define VMW0() asm volatile("s_waitcnt vmcnt(0)" ::: "memory")
#define SB0() __builtin_amdgcn_sched_barrier(0)
#define LGKM0()                                             \
  do {                                                      \
    SB0();                                                  \
    asm volatile("s_waitcnt lgkmcnt(0)" ::: "memory");      \
    SB0();                                                  \
  } while (0)

__device__ __forceinline__ void load_lds16(const void* g, void* l) {
  __builtin_amdgcn_global_load_lds(
      (const __attribute__((address_space(1))) void*)g,
      (__attribute__((address_space(3))) void*)l,
      16, 0, 0);
}

// ---------- K1: per-block partial sums of |w| (deterministic) ----------
__global__ __launch_bounds__(256) void k_abs_partial(const float* __restrict__ w,
                                                     double* __restrict__ partial) {
  const int tid = threadIdx.x;
  const size_t base = (size_t)blockIdx.x * 8192 + (size_t)tid * 4;
  double s = 0.0;
#pragma unroll
  for (int it = 0; it < 8; ++it) {
    const float4 v = *reinterpret_cast<const float4*>(w + base + (size_t)it * 1024);
    s += (double)fabsf(v.x) + (double)fabsf(v.y) + (double)fabsf(v.z) + (double)fabsf(v.w);
  }
  __shared__ double sd[256];
  sd[tid] = s;
  __syncthreads();
  for (int off = 128; off > 0; off >>= 1) {
    if (tid < off) sd[tid] += sd[tid + off];
    __syncthreads();
  }
  if (tid == 0) partial[blockIdx.x] = sd[0];
}

// ---------- K2: finalize gamma (fp32 like numpy) ----------
__global__ __launch_bounds__(256) void k_abs_final(const double* __restrict__ partial,
                                                   float* __restrict__ gamma_out) {
  const int tid = threadIdx.x;
  double s = 0.0;
  for (int i = tid; i < 2048; i += 256) s += partial[i];
  __shared__ double sd[256];
  sd[tid] = s;
  __syncthreads();
  for (int off = 128; off > 0; off >>= 1) {
    if (tid < off) sd[tid] += sd[tid + off];
    __syncthreads();
  }
  if (tid == 0) {
    float g = (float)(sd[0] / 16777216.0);  // mean over 4096*4096
    gamma_out[0] = g + 1e-5f;
  }
}

// ---------- K3: quantize W -> ternary int8 ----------
__global__ __launch_bounds__(256) void k_quant(const float* __restrict__ w,
                                               const float* __restrict__ gamma_p,
                                               int* __restrict__ qb) {
  const float g = gamma_p[0];
  const size_t n4 = (size_t)N_DIM * K_DIM / 4;
  const size_t stride = (size_t)gridDim.x * blockDim.x;
  for (size_t i = (size_t)blockIdx.x * blockDim.x + threadIdx.x; i < n4; i += stride) {
    const float4 v = reinterpret_cast<const float4*>(w)[i];
    float r;
    int a, b, c, d;
    r = rintf(v.x / g); a = (r >= 1.0f) ? 1 : ((r <= -1.0f) ? -1 : 0);
    r = rintf(v.y / g); b = (r >= 1.0f) ? 1 : ((r <= -1.0f) ? -1 : 0);
    r = rintf(v.z / g); c = (r >= 1.0f) ? 1 : ((r <= -1.0f) ? -1 : 0);
    r = rintf(v.w / g); d = (r >= 1.0f) ? 1 : ((r <= -1.0f) ? -1 : 0);
    qb[i] = (a & 0xff) | ((b & 0xff) << 8) | ((c & 0xff) << 16) | ((d & 0xff) << 24);
  }
}

// ---------- K4: x fp32 -> per-row-scaled int8 ----------
__global__ __launch_bounds__(256) void k_quant_x(const float* __restrict__ x,
                                                 signed char* __restrict__ xq,
                                                 float* __restrict__ xs) {
  const int row = blockIdx.x;  // 8192
  const int tid = threadIdx.x;
  const float* xr = x + (size_t)row * K_DIM;
  float4 v[4];
  float am = 0.0f;
#pragma unroll
  for (int i = 0; i < 4; ++i) {
    v[i] = reinterpret_cast<const float4*>(xr)[tid * 4 + i];
    am = fmaxf(am, fmaxf(fmaxf(fabsf(v[i].x), fabsf(v[i].y)),
                         fmaxf(fabsf(v[i].z), fabsf(v[i].w))));
  }
  for (int off = 32; off > 0; off >>= 1) am = fmaxf(am, __shfl_down(am, off));
  __shared__ float sm[4];
  if ((tid & 63) == 0) sm[tid >> 6] = am;
  __syncthreads();
  const float bm = fmaxf(fmaxf(fmaxf(sm[0], sm[1]), fmaxf(sm[2], sm[3])), 1e-20f);
  if (tid == 0) xs[row] = bm / 127.0f;
  const float inv = 127.0f / bm;
  union { signed char c[16]; int4 q; } u;
#pragma unroll
  for (int i = 0; i < 4; ++i) {
    u.c[i * 4 + 0] = (signed char)(int)rintf(v[i].x * inv);
    u.c[i * 4 + 1] = (signed char)(int)rintf(v[i].y * inv);
    u.c[i * 4 + 2] = (signed char)(int)rintf(v[i].z * inv);
    u.c[i * 4 + 3] = (signed char)(int)rintf(v[i].w * inv);
  }
  *reinterpret_cast<int4*>(xq + (size_t)row * K_DIM + tid * 16) = u.q;
}

// ---------- K5: 128x256 i8 MFMA GEMM, 3-buf counted, 2 blocks/CU ----------
// i8 LDS swizzle (verified R13/R15/R18/R23): 64B rows = 4x16B slots; logical
// slot c at phys slot c ^ ((row>>1)&3); inverse-swizzled glds source +
// swizzled ds_read. Per buffer: A[128][64] at 0 (8KB), B[256][64] at 8192.
__global__ __launch_bounds__(512, 4) void k_gemm(const signed char* __restrict__ Aq,
                                                 const signed char* __restrict__ Bq,
                                                 const float* __restrict__ xs,
                                                 const float* __restrict__ bias,
                                                 float* __restrict__ C) {
  __shared__ unsigned char lds[3][24576];  // 72 KiB -> 2 blocks/CU (144 KiB)

  const int tid = threadIdx.x;
  const int wid = tid >> 6;   // 0..7
  const int lane = tid & 63;
  const int wm = wid >> 2;    // 0..1 (row half)
  const int wn = wid & 3;     // 0..3 (col quarter)
  const int l15 = lane & 15;
  const int l4 = lane >> 4;   // 0..3

  // bijective XCD col-chunk swizzle: 1024 blocks = 8 XCDs x 128; XCD c owns
  // B col-panels {2c, 2c+1} (2MB i8, L2-resident); rows stream.
  const int c8 = blockIdx.x & 7;
  const int idx = blockIdx.x >> 3;            // 0..127
  const int bcol = (c8 * 2 + (idx & 1)) * BN;
  const int brow = (idx >> 1) * BM;

  // staging: thread covers (row = tid>>2, slot = tid&3); source pre-inverse-swizzled
  const int srow = tid >> 2;
  const int scol = ((tid & 3) ^ ((tid >> 3) & 3)) << 4;
  // ds_read: phys slot = l4 ^ ((row>>1)&3)
  const int rdoff = ((l4 ^ ((l15 >> 1) & 3)) << 4);

#define STAGE_ALL(buf, kt)                                                          \
  do {                                                                              \
    load_lds16(Aq + (size_t)(brow + srow) * K_DIM + (kt)*64 + scol,                 \
               (char*)&lds[buf][0] + (size_t)wid * 1024);                           \
    load_lds16(Bq + (size_t)(bcol + srow) * K_DIM + (kt)*64 + scol,                 \
               (char*)&lds[buf][8192] + (size_t)wid * 1024);                        \
    load_lds16(Bq + (size_t)(bcol + 128 + srow) * K_DIM + (kt)*64 + scol,           \
               (char*)&lds[buf][16384] + (size_t)wid * 1024);                       \
    SB0();                                                                          \
  } while (0)

#define RD8(buf)                                                                    \
  do {                                                                              \
    _Pragma("unroll") for (int i = 0; i < 4; ++i)                                   \
      fa[i] = *reinterpret_cast<const vi4*>(                                        \
          &lds[buf][0] + (size_t)(wm * 64 + i * 16 + l15) * 64 + rdoff);            \
    _Pragma("unroll") for (int p = 0; p < 4; ++p)                                   \
      fb[p] = *reinterpret_cast<const vi4*>(                                        \
          &lds[buf][8192] + (size_t)(wn * 64 + p * 16 + l15) * 64 + rdoff);         \
    SB0();                                                                          \
  } while (0)

#define MFMA16()                                                                    \
  do {                                                                              \
    __builtin_amdgcn_s_setprio(1);                                                  \
    _Pragma("unroll") for (int i = 0; i < 4; ++i)                                   \
      _Pragma("unroll") for (int p = 0; p < 4; ++p)                                 \
        acc[i][p] = __builtin_amdgcn_mfma_i32_16x16x64_i8(fa[i], fb[p],             \
                                                          acc[i][p], 0, 0, 0);      \
    __builtin_amdgcn_s_setprio(0);                                                  \
  } while (0)

  vi4 acc[4][4];
#pragma unroll
  for (int i = 0; i < 4; ++i)
#pragma unroll
    for (int p = 0; p < 4; ++p)
#pragma unroll
      for (int e = 0; e < 4; ++e) acc[i][p][e] = 0;

  vi4 fa[4], fb[4];

  // prologue: tile0 -> buf0, tile1 -> buf1
  STAGE_ALL(0, 0);
  STAGE_ALL(1, 1);
  VMW3();  // tile0's 3 (oldest) landed; tile1's 3 in flight
  BAR();

  int cur = 0;
  for (int t = 0; t < 62; ++t) {
    const int stg = (cur == 0) ? 2 : cur - 1;  // (t+2)%3
    RD8(cur);                // 8 ds_read_b128 (tile t)
    STAGE_ALL(stg, t + 2);   // 3 glds (tile t+2); 2-tile slack, WAR-safe
    LGKM0();                 // own frags landed; staging stays in flight
    MFMA16();
    VMW3();                  // tile t+1's 3 landed (3 newest = t+2's) -> publish
    BAR();
    cur = (cur == 2) ? 0 : cur + 1;
  }
  // tile 62 (cur = 2): tile 63 already staged (at t=61 into buf0); full drain
  RD8(cur);
  LGKM0();
  MFMA16();
  VMW0();
  BAR();
  // tile 63 (buf 0)
  RD8(0);
  LGKM0();
  MFMA16();

  // ---- epilogue: C/D layout col=lane&15, row=(lane>>4)*4+j; dequant + bias ----
  float bi[4];
#pragma unroll
  for (int p = 0; p < 4; ++p) bi[p] = bias[bcol + wn * 64 + p * 16 + l15];
#pragma unroll
  for (int i = 0; i < 4; ++i) {
#pragma unroll
    for (int j = 0; j < 4; ++j) {
      const int row = brow + wm * 64 + i * 16 + l4 * 4 + j;
      const float sc = xs[row];
      float* crow = C + (size_t)row * N_DIM + bcol + wn * 64 + l15;
#pragma unroll
      for (int p = 0; p < 4; ++p) crow[p * 16] = (float)acc[i][p][j] * sc + bi[p];
    }
  }
#undef STAGE_ALL
#undef RD8
#undef MFMA16
}

extern "C" void kernel_launch(void* const* d_in, const int* in_sizes, int n_in,
                              void* d_out, int out_size, void* d_ws, size_t ws_size,
                              hipStream_t stream) {
  (void)in_sizes; (void)n_in; (void)out_size; (void)ws_size;
  const float* x = (const float*)d_in[0];
  const float* w = (const float*)d_in[1];
  const float* bias = (const float*)d_in[2];
  float* out = (float*)d_out;

  char* ws = (char*)d_ws;
  signed char* xq = (signed char*)ws;                                   // 32 MB
  signed char* qb = (signed char*)(ws + (size_t)M_DIM * K_DIM);         // 16 MB
  float* xs = (float*)(ws + (size_t)M_DIM * K_DIM + (size_t)N_DIM * K_DIM);  // 32 KB
  double* partial = (double*)((char*)xs + M_DIM * sizeof(float));
  float* gamma = (float*)(partial + 2048);

  k_abs_partial<<<2048, 256, 0, stream>>>(w, partial);
  k_abs_final<<<1, 256, 0, stream>>>(partial, gamma);
  k_quant<<<2048, 256, 0, stream>>>(w, gamma, (int*)qb);
  k_quant_x<<<M_DIM, 256, 0, stream>>>(x, xq, xs);

  k_gemm<<<1024, 512, 0, stream>>>(xq, qb, xs, bias, out);
}

// Round 25
// 199.820 us; speedup vs baseline: 1.1089x; 1.0164x over previous
//
#include <hip/hip_runtime.h>
#include <stdint.h>

// QuantizedLinear (BitNet ternary): out = x @ q^T + bias
// INT8 path (absmax 3.06). R25: LDS-traffic reduction — 4 waves of 64x128
// (read amplification 64->48 KB per 128x256 block-tile; R18 showed smaller
// tiles RAISE traffic, bigger wave-tiles LOWER it). 3-buf counted VMW(6)
// schedule (R24-verified), 2 blocks/CU via launch_bounds(256,2) + 72KB LDS.

#define M_DIM 8192
#define N_DIM 4096
#define K_DIM 4096
#define BM 128
#define BN 256
#define BK 64

typedef __attribute__((ext_vector_type(4))) int vi4;

#define BAR() asm volatile("s_barrier" ::: "memory")
#define VMW6() asm volatile("s_waitcnt vmcnt(6)" ::: "memory")
#define VMW0() asm volatile("s_waitcnt vmcnt(0)" ::: "memory")
#define SB0() __builtin_amdgcn_sched_barrier(0)
#define LGKM0()                                             \
  do {                                                      \
    SB0();                                                  \
    asm volatile("s_waitcnt lgkmcnt(0)" ::: "memory");      \
    SB0();                                                  \
  } while (0)

__device__ __forceinline__ void load_lds16(const void* g, void* l) {
  __builtin_amdgcn_global_load_lds(
      (const __attribute__((address_space(1))) void*)g,
      (__attribute__((address_space(3))) void*)l,
      16, 0, 0);
}

// ---------- K1: per-block partial sums of |w| (deterministic) ----------
__global__ __launch_bounds__(256) void k_abs_partial(const float* __restrict__ w,
                                                     double* __restrict__ partial) {
  const int tid = threadIdx.x;
  const size_t base = (size_t)blockIdx.x * 8192 + (size_t)tid * 4;
  double s = 0.0;
#pragma unroll
  for (int it = 0; it < 8; ++it) {
    const float4 v = *reinterpret_cast<const float4*>(w + base + (size_t)it * 1024);
    s += (double)fabsf(v.x) + (double)fabsf(v.y) + (double)fabsf(v.z) + (double)fabsf(v.w);
  }
  __shared__ double sd[256];
  sd[tid] = s;
  __syncthreads();
  for (int off = 128; off > 0; off >>= 1) {
    if (tid < off) sd[tid] += sd[tid + off];
    __syncthreads();
  }
  if (tid == 0) partial[blockIdx.x] = sd[0];
}

// ---------- K2: finalize gamma (fp32 like numpy) ----------
__global__ __launch_bounds__(256) void k_abs_final(const double* __restrict__ partial,
                                                   float* __restrict__ gamma_out) {
  const int tid = threadIdx.x;
  double s = 0.0;
  for (int i = tid; i < 2048; i += 256) s += partial[i];
  __shared__ double sd[256];
  sd[tid] = s;
  __syncthreads();
  for (int off = 128; off > 0; off >>= 1) {
    if (tid < off) sd[tid] += sd[tid + off];
    __syncthreads();
  }
  if (tid == 0) {
    float g = (float)(sd[0] / 16777216.0);  // mean over 4096*4096
    gamma_out[0] = g + 1e-5f;
  }
}

// ---------- K3: quantize W -> ternary int8 ----------
__global__ __launch_bounds__(256) void k_quant(const float* __restrict__ w,
                                               const float* __restrict__ gamma_p,
                                               int* __restrict__ qb) {
  const float g = gamma_p[0];
  const size_t n4 = (size_t)N_DIM * K_DIM / 4;
  const size_t stride = (size_t)gridDim.x * blockDim.x;
  for (size_t i = (size_t)blockIdx.x * blockDim.x + threadIdx.x; i < n4; i += stride) {
    const float4 v = reinterpret_cast<const float4*>(w)[i];
    float r;
    int a, b, c, d;
    r = rintf(v.x / g); a = (r >= 1.0f) ? 1 : ((r <= -1.0f) ? -1 : 0);
    r = rintf(v.y / g); b = (r >= 1.0f) ? 1 : ((r <= -1.0f) ? -1 : 0);
    r = rintf(v.z / g); c = (r >= 1.0f) ? 1 : ((r <= -1.0f) ? -1 : 0);
    r = rintf(v.w / g); d = (r >= 1.0f) ? 1 : ((r <= -1.0f) ? -1 : 0);
    qb[i] = (a & 0xff) | ((b & 0xff) << 8) | ((c & 0xff) << 16) | ((d & 0xff) << 24);
  }
}

// ---------- K4: x fp32 -> per-row-scaled int8 ----------
__global__ __launch_bounds__(256) void k_quant_x(const float* __restrict__ x,
                                                 signed char* __restrict__ xq,
                                                 float* __restrict__ xs) {
  const int row = blockIdx.x;  // 8192
  const int tid = threadIdx.x;
  const float* xr = x + (size_t)row * K_DIM;
  float4 v[4];
  float am = 0.0f;
#pragma unroll
  for (int i = 0; i < 4; ++i) {
    v[i] = reinterpret_cast<const float4*>(xr)[tid * 4 + i];
    am = fmaxf(am, fmaxf(fmaxf(fabsf(v[i].x), fabsf(v[i].y)),
                         fmaxf(fabsf(v[i].z), fabsf(v[i].w))));
  }
  for (int off = 32; off > 0; off >>= 1) am = fmaxf(am, __shfl_down(am, off));
  __shared__ float sm[4];
  if ((tid & 63) == 0) sm[tid >> 6] = am;
  __syncthreads();
  const float bm = fmaxf(fmaxf(fmaxf(sm[0], sm[1]), fmaxf(sm[2], sm[3])), 1e-20f);
  if (tid == 0) xs[row] = bm / 127.0f;
  const float inv = 127.0f / bm;
  union { signed char c[16]; int4 q; } u;
#pragma unroll
  for (int i = 0; i < 4; ++i) {
    u.c[i * 4 + 0] = (signed char)(int)rintf(v[i].x * inv);
    u.c[i * 4 + 1] = (signed char)(int)rintf(v[i].y * inv);
    u.c[i * 4 + 2] = (signed char)(int)rintf(v[i].z * inv);
    u.c[i * 4 + 3] = (signed char)(int)rintf(v[i].w * inv);
  }
  *reinterpret_cast<int4*>(xq + (size_t)row * K_DIM + tid * 16) = u.q;
}

// ---------- K5: 128x256 i8 GEMM, 4 waves of 64x128, 3-buf counted ----------
// i8 LDS swizzle (verified R13..R24): 64B rows = 4x16B slots; logical slot c
// at phys slot c ^ ((row>>1)&3); inverse-swizzled glds source + swizzled
// ds_read. Per buffer: A[128][64] at 0 (8KB), B[256][64] at 8192 (16KB).
__global__ __launch_bounds__(256, 2) void k_gemm(const signed char* __restrict__ Aq,
                                                 const signed char* __restrict__ Bq,
                                                 const float* __restrict__ xs,
                                                 const float* __restrict__ bias,
                                                 float* __restrict__ C) {
  __shared__ unsigned char lds[3][24576];  // 72 KiB -> 2 blocks/CU (144 KiB)

  const int tid = threadIdx.x;
  const int wid = tid >> 6;   // 0..3
  const int lane = tid & 63;
  const int wm = wid >> 1;    // 0..1 (row half, 64 rows)
  const int wn = wid & 1;     // 0..1 (col half, 128 cols)
  const int l15 = lane & 15;
  const int l4 = lane >> 4;   // 0..3

  // bijective XCD col-chunk swizzle: 1024 blocks = 8 XCDs x 128; XCD c owns
  // B col-panels {2c, 2c+1} (2MB i8, L2-resident); rows stream.
  const int c8 = blockIdx.x & 7;
  const int idx = blockIdx.x >> 3;            // 0..127
  const int bcol = (c8 * 2 + (idx & 1)) * BN;
  const int brow = (idx >> 1) * BM;

  // staging (256 thr x 16B = 4KB/issue): issue covers 64 rows; thread row =
  // tid>>2, slot = tid&3. Swizzle key (row>>1)&3 = (tid>>3)&3 (64-row issue
  // offsets are 0 mod 8-row stripe). Dest = issue*4096 + wid*1024 + lane*16.
  const int srow = tid >> 2;
  const int scol = ((tid & 3) ^ ((tid >> 3) & 3)) << 4;
  // ds_read: phys slot = l4 ^ ((row>>1)&3); row ≡ l15 (mod 16)
  const int rdoff = ((l4 ^ ((l15 >> 1) & 3)) << 4);

#define STAGE_ALL(buf, kt)                                                          \
  do {                                                                              \
    _Pragma("unroll") for (int a = 0; a < 2; ++a)                                   \
      load_lds16(Aq + (size_t)(brow + a * 64 + srow) * K_DIM + (kt)*64 + scol,      \
                 (char*)&lds[buf][0] + a * 4096 + (size_t)wid * 1024);              \
    _Pragma("unroll") for (int b = 0; b < 4; ++b)                                   \
      load_lds16(Bq + (size_t)(bcol + b * 64 + srow) * K_DIM + (kt)*64 + scol,      \
                 (char*)&lds[buf][8192] + b * 4096 + (size_t)wid * 1024);           \
    SB0();                                                                          \
  } while (0)

#define RD12(buf)                                                                   \
  do {                                                                              \
    _Pragma("unroll") for (int i = 0; i < 4; ++i)                                   \
      fa[i] = *reinterpret_cast<const vi4*>(                                        \
          &lds[buf][0] + (size_t)(wm * 64 + i * 16 + l15) * 64 + rdoff);            \
    _Pragma("unroll") for (int p = 0; p < 8; ++p)                                   \
      fb[p] = *reinterpret_cast<const vi4*>(                                        \
          &lds[buf][8192] + (size_t)(wn * 128 + p * 16 + l15) * 64 + rdoff);        \
    SB0();                                                                          \
  } while (0)

#define MFMA32()                                                                    \
  do {                                                                              \
    __builtin_amdgcn_s_setprio(1);                                                  \
    _Pragma("unroll") for (int i = 0; i < 4; ++i)                                   \
      _Pragma("unroll") for (int p = 0; p < 8; ++p)                                 \
        acc[i][p] = __builtin_amdgcn_mfma_i32_16x16x64_i8(fa[i], fb[p],             \
                                                          acc[i][p], 0, 0, 0);      \
    __builtin_amdgcn_s_setprio(0);                                                  \
  } while (0)

  vi4 acc[4][8];
#pragma unroll
  for (int i = 0; i < 4; ++i)
#pragma unroll
    for (int p = 0; p < 8; ++p)
#pragma unroll
      for (int e = 0; e < 4; ++e) acc[i][p][e] = 0;

  vi4 fa[4], fb[8];

  // prologue: tile0 -> buf0, tile1 -> buf1
  STAGE_ALL(0, 0);
  STAGE_ALL(1, 1);
  VMW6();  // tile0's 6 (oldest) landed; tile1's 6 in flight
  BAR();

  int cur = 0;
  for (int t = 0; t < 62; ++t) {
    const int stg = (cur == 0) ? 2 : cur - 1;  // (t+2)%3
    RD12(cur);               // 12 ds_read_b128 (tile t)
    STAGE_ALL(stg, t + 2);   // 6 glds (tile t+2); 2-tile slack, WAR-safe
    LGKM0();                 // own frags landed; staging stays in flight
    MFMA32();
    VMW6();                  // tile t+1's 6 landed (6 newest = t+2's) -> publish
    BAR();
    cur = (cur == 2) ? 0 : cur + 1;
  }
  // tile 62 (cur = 2): tile 63 already staged (at t=61 into buf0); full drain
  RD12(cur);
  LGKM0();
  MFMA32();
  VMW0();
  BAR();
  // tile 63 (buf 0)
  RD12(0);
  LGKM0();
  MFMA32();

  // ---- epilogue: C/D layout col=lane&15, row=(lane>>4)*4+j; dequant + bias ----
  float bi[8];
#pragma unroll
  for (int p = 0; p < 8; ++p) bi[p] = bias[bcol + wn * 128 + p * 16 + l15];
#pragma unroll
  for (int i = 0; i < 4; ++i) {
#pragma unroll
    for (int j = 0; j < 4; ++j) {
      const int row = brow + wm * 64 + i * 16 + l4 * 4 + j;
      const float sc = xs[row];
      float* crow = C + (size_t)row * N_DIM + bcol + wn * 128 + l15;
#pragma unroll
      for (int p = 0; p < 8; ++p) crow[p * 16] = (float)acc[i][p][j] * sc + bi[p];
    }
  }
#undef STAGE_ALL
#undef RD12
#undef MFMA32
}

extern "C" void kernel_launch(void* const* d_in, const int* in_sizes, int n_in,
                              void* d_out, int out_size, void* d_ws, size_t ws_size,
                              hipStream_t stream) {
  (void)in_sizes; (void)n_in; (void)out_size; (void)ws_size;
  const float* x = (const float*)d_in[0];
  const float* w = (const float*)d_in[1];
  const float* bias = (const float*)d_in[2];
  float* out = (float*)d_out;

  char* ws = (char*)d_ws;
  signed char* xq = (signed char*)ws;                                   // 32 MB
  signed char* qb = (signed char*)(ws + (size_t)M_DIM * K_DIM);         // 16 MB
  float* xs = (float*)(ws + (size_t)M_DIM * K_DIM + (size_t)N_DIM * K_DIM);  // 32 KB
  double* partial = (double*)((char*)xs + M_DIM * sizeof(float));
  float* gamma = (float*)(partial + 2048);

  k_abs_partial<<<2048, 256, 0, stream>>>(w, partial);
  k_abs_final<<<1, 256, 0, stream>>>(partial, gamma);
  k_quant<<<2048, 256, 0, stream>>>(w, gamma, (int*)qb);
  k_quant_x<<<M_DIM, 256, 0, stream>>>(x, xq, xs);

  k_gemm<<<1024, 256, 0, stream>>>(xq, qb, xs, bias, out);
}